// Round 5
// baseline (50.401 us; speedup 1.0000x reference)
//
#include <hip/hip_runtime.h>

typedef _Float16 f16x8 __attribute__((ext_vector_type(8)));
typedef float    f32x4 __attribute__((ext_vector_type(4)));

#define BATCH 65536
#define NIN   128
#define NOUT  128

#define L2E   1.4426950408889634f
#define SQL2E 1.2011224087864498f     /* sqrt(log2 e) */
#define EM2   0.1353352832366127f     /* e^-2 */

// ---------------------------------------------------------------------------
// W2 layout (fp16, by kan_prep): 36 tiles of 8 KB (one per k-step).
// Tile ks, chunk c = nb*64 + lane (16 B per chunk, lane = lhi*16 + l15):
//   n = nb*16 + l15, e = 0..7:
//     ks < 32  -> coeffs[n][j = lhi*32 + ks][g = e]            (basis)
//     ks >= 32 -> base_w[n][j = lhi*32 + (ks-32)*8 + e]        (silu)
// MFMA k_local = lhi*8 + e. Per nb-fragment ds_read: 64 lanes read 1024
// CONSECUTIVE bytes -> conflict-free (verified 0). Pairs of tiles (16 KB)
// staged linearly via global_load_lds, double-buffered.
// ---------------------------------------------------------------------------

__global__ __launch_bounds__(256) void kan_prep(const float* __restrict__ coeffs,
                                                const float* __restrict__ base_w,
                                                _Float16* __restrict__ W2) {
    int t = blockIdx.x * 256 + threadIdx.x;   // chunk id, 0..18431
    int ks   = t >> 9;
    int c    = t & 511;
    int nb   = c >> 6;
    int lane = c & 63;
    int lhi  = lane >> 4;
    int l15  = lane & 15;
    int n    = nb * 16 + l15;
    const float* src;
    if (ks < 32) src = coeffs + ((size_t)n * 128 + lhi * 32 + ks) * 8;
    else         src = base_w + (size_t)n * 128 + lhi * 32 + (ks - 32) * 8;
    f16x8 v;
#pragma unroll
    for (int e = 0; e < 8; ++e) v[e] = (_Float16)src[e];
    *(f16x8*)((char*)W2 + (size_t)t * 16) = v;
}

__device__ __forceinline__ void gll16(const void* g, void* l) {
    __builtin_amdgcn_global_load_lds(
        (const __attribute__((address_space(1))) unsigned int*)g,
        (__attribute__((address_space(3))) unsigned int*)l, 16, 0, 0);
}

// b_g = exp(-(t-g)^2), g = 0..7, t = 3.5*(x+1); 2 exp + mul-chain.
// b_{g+1} = b_g * r_g with r_g = e^{2t-2g-1}; r_{g+1} = r_g * e^-2.
__device__ __forceinline__ f16x8 basis8r(float t) {
    float u = t * SQL2E;
    float b = __builtin_amdgcn_exp2f(-(u * u));                                   // e^{-t^2}
    float r = __builtin_amdgcn_exp2f(__builtin_fmaf(t, 2.0f * L2E, -L2E));        // e^{2t-1}
    f16x8 o;
    o[0] = (_Float16)b;
#pragma unroll
    for (int g = 1; g < 8; ++g) {
        b = b * r;
        r = r * EM2;
        o[g] = (_Float16)b;
    }
    return o;
}

__device__ __forceinline__ float silu1(float xv) {
    float p = __builtin_amdgcn_exp2f(-xv * L2E);
    return xv * __builtin_amdgcn_rcpf(1.0f + p);
}

// 256 threads = 4 waves (2x2): wave owns 32 rows x 64 cols (m=2, nb=4).
// acc = 32 VGPR -> target <=128 VGPR -> 4 waves/SIMD, 16 waves/CU.
// Grid 1024 (64 rows/block) -> 4 blocks/CU, staggered barrier domains.
__global__ __launch_bounds__(256, 4) void kan_main(const float* __restrict__ x,
                                                   const float* __restrict__ centers,
                                                   const _Float16* __restrict__ W2,
                                                   float* __restrict__ out) {
    __shared__ _Float16 smem[2][8192];   // 2 x 16 KB (2 k-step tiles each)

    const int tid  = threadIdx.x;
    const int lane = tid & 63;
    const int w    = tid >> 6;
    const int wr   = w >> 1;             // row half (0/1): +32 rows
    const int wc   = w & 1;              // col half (0/1): +64 cols
    const int l15  = lane & 15;
    const int lhi  = lane >> 4;
    const int row0 = blockIdx.x * 64 + wr * 32;
    const int col0 = wc * 64;

    // per-lane x base: rows row0 + m*16 + l15, col stripe lhi*32 + ...
    const float* xp = x + (size_t)(row0 + l15) * NIN + lhi * 32;

    f32x4 acc[2][4];
#pragma unroll
    for (int m = 0; m < 2; ++m)
#pragma unroll
        for (int nb = 0; nb < 4; ++nb) acc[m][nb] = (f32x4){0.f, 0.f, 0.f, 0.f};

    const char* w2base = (const char*)W2;
    // stage one 16 KB group (2 k-step tiles): 256 threads x 4 chunks, linear
#define STAGE(buf, grp)                                                         \
    do {                                                                        \
        const char* _s = w2base + (size_t)(grp) * 16384 + (size_t)tid * 16;     \
        char*       _d = (char*)&smem[(buf)][0] + (size_t)tid * 16;             \
        _Pragma("unroll")                                                       \
        for (int _i = 0; _i < 4; ++_i) gll16(_s + _i * 4096, _d + _i * 4096);   \
    } while (0)

    STAGE(0, 0);
    __syncthreads();

    // ---- 16 basis groups of 2 k-steps (K = 1024); kstep ks = g*2 + t2 ----
#pragma unroll
    for (int g = 0; g < 16; ++g) {
        const int cur = g & 1;
        STAGE(cur ^ 1, g + 1);           // g == 15 stages first silu pair
        float2 xb0 = *(const float2*)(xp + g * 2);          // m=0, cols 2g,2g+1
        float2 xb1 = *(const float2*)(xp + 2048 + g * 2);   // m=1
#pragma unroll
        for (int t2 = 0; t2 < 2; ++t2) { // j = lhi*32 + g*2 + t2
            f16x8 a0 = basis8r(__builtin_fmaf(t2 ? xb0.y : xb0.x, 3.5f, 3.5f));
            f16x8 a1 = basis8r(__builtin_fmaf(t2 ? xb1.y : xb1.x, 3.5f, 3.5f));
            const _Float16* bp = &smem[cur][t2 * 4096 + (wc * 4) * 512 + lane * 8];
#pragma unroll
            for (int nb = 0; nb < 4; ++nb) {
                f16x8 b = *(const f16x8*)(bp + nb * 512);
                acc[0][nb] = __builtin_amdgcn_mfma_f32_16x16x32_f16(a0, b, acc[0][nb], 0, 0, 0);
                acc[1][nb] = __builtin_amdgcn_mfma_f32_16x16x32_f16(a1, b, acc[1][nb], 0, 0, 0);
            }
        }
        __syncthreads();
    }

    // ---- 2 silu groups (k-steps 32..35, K = 128) ----
#pragma unroll
    for (int g = 16; g < 18; ++g) {
        const int cur = g & 1;
        if (g < 17) STAGE(cur ^ 1, g + 1);
#pragma unroll
        for (int t2 = 0; t2 < 2; ++t2) { // silu kstep s: j = lhi*32 + s*8 + e
            const int s = (g - 16) * 2 + t2;
            f16x8 a[2];
#pragma unroll
            for (int m = 0; m < 2; ++m) {
                f32x4 v0 = *(const f32x4*)(xp + m * 2048 + s * 8);
                f32x4 v1 = *(const f32x4*)(xp + m * 2048 + s * 8 + 4);
#pragma unroll
                for (int e = 0; e < 4; ++e) {
                    a[m][e]     = (_Float16)silu1(v0[e]);
                    a[m][4 + e] = (_Float16)silu1(v1[e]);
                }
            }
            const _Float16* bp = &smem[cur][t2 * 4096 + (wc * 4) * 512 + lane * 8];
#pragma unroll
            for (int nb = 0; nb < 4; ++nb) {
                f16x8 b = *(const f16x8*)(bp + nb * 512);
                acc[0][nb] = __builtin_amdgcn_mfma_f32_16x16x32_f16(a[0], b, acc[0][nb], 0, 0, 0);
                acc[1][nb] = __builtin_amdgcn_mfma_f32_16x16x32_f16(a[1], b, acc[1][nb], 0, 0, 0);
            }
        }
        if (g < 17) __syncthreads();
    }

    // ---- Epilogue: D row = m*16 + lhi*4 + r, col = col0 + nb*16 + l15 ----
#pragma unroll
    for (int m = 0; m < 2; ++m)
#pragma unroll
        for (int nb = 0; nb < 4; ++nb)
#pragma unroll
            for (int r = 0; r < 4; ++r)
                out[(size_t)(row0 + m * 16 + lhi * 4 + r) * NOUT + col0 + nb * 16 + l15] = acc[m][nb][r];
}

extern "C" void kernel_launch(void* const* d_in, const int* in_sizes, int n_in,
                              void* d_out, int out_size, void* d_ws, size_t ws_size,
                              hipStream_t stream) {
    const float* x       = (const float*)d_in[0];
    const float* coeffs  = (const float*)d_in[1];
    const float* base_w  = (const float*)d_in[2];
    const float* centers = (const float*)d_in[3];
    _Float16* W2 = (_Float16*)d_ws;   // 36 * 8192 = 294912 bytes

    kan_prep<<<dim3(72), dim3(256), 0, stream>>>(coeffs, base_w, W2);
    kan_main<<<dim3(BATCH / 64), dim3(256), 0, stream>>>(x, centers, W2, (float*)d_out);
}

// Round 6
// 45.619 us; speedup vs baseline: 1.1048x; 1.1048x over previous
//
#include <hip/hip_runtime.h>

typedef _Float16 f16x8  __attribute__((ext_vector_type(8)));
typedef float    f32x4  __attribute__((ext_vector_type(4)));
typedef float    f32x16 __attribute__((ext_vector_type(16)));

#define BATCH 65536
#define NIN   128
#define NOUT  128

#define L2E   1.4426950408889634f
#define SQL2E 1.2011224087864498f     /* sqrt(log2 e) */
#define EM2   0.1353352832366127f     /* e^-2 */

// ---------------------------------------------------------------------------
// MFMA shape: 32x32x16 f16.  A-frag: lane l -> row = l&31, k = (l>>5)*8 + e.
// B-frag: lane l -> col = l&31, k = (l>>5)*8 + e.  C/D: col = l&31,
// row = (reg&3) + 8*(reg>>2) + 4*(l>>5)   [m74/m101].
//
// K-order (total K = 1152 = 72 ksteps of 16):
//   basis ksteps ks = g*8 + t2 (g = 0..7, t2 = 0..7):
//       k = ks*16 + sub*8 + e  ->  j = g*16 + sub*8 + t2, grid idx = e
//       => lane's A-frag = basis8(x[row][g*16 + sub*8 + t2]); over a group
//          the lane consumes 8 CONSECUTIVE x floats (2 f32x4 loads).
//   silu ksteps ks = 64 + s (s = 0..7):  k = 1024 + j,
//       j = s*16 + sub*8 + e  (8 consecutive floats per lane per kstep).
//
// W3 (by kan_prep): 72 tiles x 4 KB; tile ks, chunk c = nbblk*64 + lane
// (16 B / chunk): col = nbblk*32 + (lane&31), sub = lane>>5, e = 0..7:
//   ks < 64 : v[e] = coeffs[col][g*16 + sub*8 + t2][e]
//   ks >= 64: v[e] = base_w[col][(ks-64)*16 + sub*8 + e]
// Per-fragment ds_read = 64 lanes x 16 B consecutive (1 KB) -> conflict-free.
// Groups of 8 tiles (32 KB) staged linearly via global_load_lds, dbuffered.
// ---------------------------------------------------------------------------

__global__ __launch_bounds__(256) void kan_prep(const float* __restrict__ coeffs,
                                                const float* __restrict__ base_w,
                                                _Float16* __restrict__ W3) {
    int t = blockIdx.x * 256 + threadIdx.x;   // chunk id, 0..18431
    int ks   = t >> 8;
    int c    = t & 255;
    int nbb  = c >> 6;
    int lane = c & 63;
    int sub  = lane >> 5;
    int col  = nbb * 32 + (lane & 31);
    f16x8 v;
    if (ks < 64) {
        int g = ks >> 3, t2 = ks & 7;
        const float* src = coeffs + ((size_t)col * 128 + g * 16 + sub * 8 + t2) * 8;
#pragma unroll
        for (int e = 0; e < 8; ++e) v[e] = (_Float16)src[e];
    } else {
        const float* src = base_w + (size_t)col * 128 + (ks - 64) * 16 + sub * 8;
#pragma unroll
        for (int e = 0; e < 8; ++e) v[e] = (_Float16)src[e];
    }
    *(f16x8*)((char*)W3 + (size_t)t * 16) = v;
}

__device__ __forceinline__ void gll16(const void* g, void* l) {
    __builtin_amdgcn_global_load_lds(
        (const __attribute__((address_space(1))) unsigned int*)g,
        (__attribute__((address_space(3))) unsigned int*)l, 16, 0, 0);
}

// b_g = exp(-(t-g)^2), g = 0..7, t = 3.5*(x+1); 2 exp + mul chain.
__device__ __forceinline__ f16x8 basis8r(float t) {
    float u = t * SQL2E;
    float b = __builtin_amdgcn_exp2f(-(u * u));                              // e^{-t^2}
    float r = __builtin_amdgcn_exp2f(__builtin_fmaf(t, 2.0f * L2E, -L2E));   // e^{2t-1}
    f16x8 o;
    o[0] = (_Float16)b;
#pragma unroll
    for (int g = 1; g < 8; ++g) {
        b = b * r;
        r = r * EM2;
        o[g] = (_Float16)b;
    }
    return o;
}

__device__ __forceinline__ float silu1(float xv) {
    float p = __builtin_amdgcn_exp2f(-xv * L2E);
    return xv * __builtin_amdgcn_rcpf(1.0f + p);
}

// 256 threads = 4 waves (2x2). Wave owns 64 rows x 64 cols (m=2 x nbb=2) of
// the block's 128x128 tile. Grid 512 -> 2 blocks/CU -> 8 waves/CU (2/SIMD).
__global__ __launch_bounds__(256, 2) void kan_main(const float* __restrict__ x,
                                                   const float* __restrict__ centers,
                                                   const _Float16* __restrict__ W3,
                                                   float* __restrict__ out) {
    __shared__ _Float16 smem[2][16384];   // 2 x 32 KB (8 k-step tiles each)

    const int tid  = threadIdx.x;
    const int lane = tid & 63;
    const int w    = tid >> 6;
    const int wr   = w >> 1;              // row half: +64 rows
    const int wc   = w & 1;               // col half: +64 cols
    const int l31  = lane & 31;
    const int sub  = lane >> 5;
    const int row0 = blockIdx.x * 128 + wr * 64;
    const int col0 = wc * 64;

    // lane's x row base (m adds 32 rows)
    const float* xp = x + (size_t)(row0 + l31) * NIN;

    f32x16 acc[2][2];
#pragma unroll
    for (int m = 0; m < 2; ++m)
#pragma unroll
        for (int nbb = 0; nbb < 2; ++nbb)
#pragma unroll
            for (int r = 0; r < 16; ++r) acc[m][nbb][r] = 0.f;

    const char* wbase = (const char*)W3;
    // stage one 32 KB group (8 tiles): 256 threads x 8 chunks of 16 B, linear
#define STAGE(buf, grp)                                                         \
    do {                                                                        \
        const char* _s = wbase + (size_t)(grp) * 32768 + (size_t)tid * 16;      \
        char*       _d = (char*)&smem[(buf)][0] + (size_t)tid * 16;             \
        _Pragma("unroll")                                                       \
        for (int _i = 0; _i < 8; ++_i) gll16(_s + _i * 4096, _d + _i * 4096);   \
    } while (0)

    STAGE(0, 0);
    __syncthreads();

    // ---- 8 basis groups of 8 ksteps (K = 1024) ----
#pragma unroll
    for (int g = 0; g < 8; ++g) {
        const int cur = g & 1;
        STAGE(cur ^ 1, g + 1);            // g == 7 stages the silu group
        // lane's 8 consecutive x values per m: j = g*16 + sub*8 + (0..7)
        f32x4 xv[2][2];
#pragma unroll
        for (int m = 0; m < 2; ++m) {
            const float* p = xp + (size_t)m * 32 * NIN + g * 16 + sub * 8;
            xv[m][0] = *(const f32x4*)p;
            xv[m][1] = *(const f32x4*)(p + 4);
        }
#pragma unroll
        for (int t2 = 0; t2 < 8; ++t2) {
            const char* bp = (const char*)&smem[cur][0] + t2 * 4096 + wc * 2048 + lane * 16;
            f16x8 b0 = *(const f16x8*)bp;
            f16x8 b1 = *(const f16x8*)(bp + 1024);
#pragma unroll
            for (int m = 0; m < 2; ++m) {
                float xs = (t2 < 4) ? xv[m][0][t2 & 3] : xv[m][1][t2 & 3];
                f16x8 a = basis8r(__builtin_fmaf(xs, 3.5f, 3.5f));
                acc[m][0] = __builtin_amdgcn_mfma_f32_32x32x16_f16(a, b0, acc[m][0], 0, 0, 0);
                acc[m][1] = __builtin_amdgcn_mfma_f32_32x32x16_f16(a, b1, acc[m][1], 0, 0, 0);
            }
        }
        __syncthreads();
    }

    // ---- silu group: 8 ksteps (K = 128), tiles in buffer 0 ----
#pragma unroll
    for (int s = 0; s < 8; ++s) {
        const char* bp = (const char*)&smem[0][0] + s * 4096 + wc * 2048 + lane * 16;
        f16x8 b0 = *(const f16x8*)bp;
        f16x8 b1 = *(const f16x8*)(bp + 1024);
#pragma unroll
        for (int m = 0; m < 2; ++m) {
            const float* p = xp + (size_t)m * 32 * NIN + s * 16 + sub * 8;
            f32x4 v0 = *(const f32x4*)p;
            f32x4 v1 = *(const f32x4*)(p + 4);
            f16x8 a;
#pragma unroll
            for (int e = 0; e < 4; ++e) {
                a[e]     = (_Float16)silu1(v0[e]);
                a[4 + e] = (_Float16)silu1(v1[e]);
            }
            acc[m][0] = __builtin_amdgcn_mfma_f32_32x32x16_f16(a, b0, acc[m][0], 0, 0, 0);
            acc[m][1] = __builtin_amdgcn_mfma_f32_32x32x16_f16(a, b1, acc[m][1], 0, 0, 0);
        }
    }

    // ---- Epilogue: row = (reg&3) + 8*(reg>>2) + 4*sub, col = l31 ----
#pragma unroll
    for (int m = 0; m < 2; ++m)
#pragma unroll
        for (int nbb = 0; nbb < 2; ++nbb)
#pragma unroll
            for (int r = 0; r < 16; ++r) {
                int crow = (r & 3) + 8 * (r >> 2) + 4 * sub;
                out[(size_t)(row0 + m * 32 + crow) * NOUT + col0 + nbb * 32 + l31] = acc[m][nbb][r];
            }
}

extern "C" void kernel_launch(void* const* d_in, const int* in_sizes, int n_in,
                              void* d_out, int out_size, void* d_ws, size_t ws_size,
                              hipStream_t stream) {
    const float* x       = (const float*)d_in[0];
    const float* coeffs  = (const float*)d_in[1];
    const float* base_w  = (const float*)d_in[2];
    const float* centers = (const float*)d_in[3];
    _Float16* W3 = (_Float16*)d_ws;   // 72 * 4096 = 294912 bytes

    kan_prep<<<dim3(72), dim3(256), 0, stream>>>(coeffs, base_w, W3);
    kan_main<<<dim3(BATCH / 128), dim3(256), 0, stream>>>(x, centers, W3, (float*)d_out);
}

// Round 8
// 37.066 us; speedup vs baseline: 1.3598x; 1.2308x over previous
//
#include <hip/hip_runtime.h>

typedef __fp16   pk16x2 __attribute__((ext_vector_type(2)));
typedef _Float16 f16x8  __attribute__((ext_vector_type(8)));
typedef float    f32x4  __attribute__((ext_vector_type(4)));
typedef float    f32x16 __attribute__((ext_vector_type(16)));

#define BATCH 65536
#define NIN   128
#define NOUT  128

#define L2E   1.4426950408889634f
#define SQL2E 1.2011224087864498f     /* sqrt(log2 e) */
#define EM2   0.1353352832366127f     /* e^-2 */

// ---------------------------------------------------------------------------
// MFMA 32x32x16 f16. A-frag: lane -> row = l&31, k = (l>>5)*8 + e.
// B-frag: lane -> col = l&31, k = (l>>5)*8 + e. C/D: col = l&31,
// row = (reg&3) + 8*(reg>>2) + 4*(l>>5).
//
// K-order (72 ksteps of 16): basis ks = g*8 + t2 (g=0..7):
//   k = ks*16 + sub*8 + e -> j = g*16 + sub*8 + t2, grid = e
//   (lane consumes 8 CONSECUTIVE x floats per group). silu ks = 64+s:
//   j = s*16 + sub*8 + e.
//
// W3 (kan_prep): 72 tiles x 4 KB; tile ks, chunk c = nbb*64 + lane (16 B):
//   col = nbb*32 + (lane&31), sub = lane>>5:
//     ks < 64 : coeffs[col][g*16 + sub*8 + t2][e]
//     ks >= 64: base_w[col][(ks-64)*16 + sub*8 + e]
// Fragment ds_read: 64 lanes x 16 B consecutive -> conflict-free (verified 0).
// ---------------------------------------------------------------------------

__global__ __launch_bounds__(256) void kan_prep(const float* __restrict__ coeffs,
                                                const float* __restrict__ base_w,
                                                _Float16* __restrict__ W3) {
    int t = blockIdx.x * 256 + threadIdx.x;   // chunk id, 0..18431
    int ks   = t >> 8;
    int c    = t & 255;
    int nbb  = c >> 6;
    int lane = c & 63;
    int sub  = lane >> 5;
    int col  = nbb * 32 + (lane & 31);
    f16x8 v;
    if (ks < 64) {
        int g = ks >> 3, t2 = ks & 7;
        const float* src = coeffs + ((size_t)col * 128 + g * 16 + sub * 8 + t2) * 8;
#pragma unroll
        for (int e = 0; e < 8; ++e) v[e] = (_Float16)src[e];
    } else {
        const float* src = base_w + (size_t)col * 128 + (ks - 64) * 16 + sub * 8;
#pragma unroll
        for (int e = 0; e < 8; ++e) v[e] = (_Float16)src[e];
    }
    *(f16x8*)((char*)W3 + (size_t)t * 16) = v;
}

__device__ __forceinline__ void gll16(const void* g, void* l) {
    __builtin_amdgcn_global_load_lds(
        (const __attribute__((address_space(1))) unsigned int*)g,
        (__attribute__((address_space(3))) unsigned int*)l, 16, 0, 0);
}

// b_g = exp(-(t-g)^2), t = 3.5*(x+1): 2 exp + mul chain, pkrtz packing.
__device__ __forceinline__ f16x8 basis8r(float t) {
    float u  = t * SQL2E;
    float b0 = __builtin_amdgcn_exp2f(-(u * u));                              // e^{-t^2}
    float r  = __builtin_amdgcn_exp2f(__builtin_fmaf(t, 2.0f * L2E, -L2E));   // e^{2t-1}
    float b1 = b0 * r; r *= EM2;
    float b2 = b1 * r; r *= EM2;
    float b3 = b2 * r; r *= EM2;
    float b4 = b3 * r; r *= EM2;
    float b5 = b4 * r; r *= EM2;
    float b6 = b5 * r; r *= EM2;
    float b7 = b6 * r;
    pk16x2 p0 = __builtin_amdgcn_cvt_pkrtz(b0, b1);
    pk16x2 p1 = __builtin_amdgcn_cvt_pkrtz(b2, b3);
    pk16x2 p2 = __builtin_amdgcn_cvt_pkrtz(b4, b5);
    pk16x2 p3 = __builtin_amdgcn_cvt_pkrtz(b6, b7);
    f16x8 o;
    o[0] = p0[0]; o[1] = p0[1]; o[2] = p1[0]; o[3] = p1[1];
    o[4] = p2[0]; o[5] = p2[1]; o[6] = p3[0]; o[7] = p3[1];
    return o;
}

__device__ __forceinline__ float silu1(float xv) {
    float p = __builtin_amdgcn_exp2f(-xv * L2E);
    return xv * __builtin_amdgcn_rcpf(1.0f + p);
}

// 256 threads = 4 row-stacked waves. Wave owns 32 rows x 128 cols (m=1,
// nbb=4): every basis value computed ONCE device-wide (d=1). Grid 512 ->
// 2 blocks/CU (64 KB LDS each) -> 8 waves/CU = 2/SIMD.
__global__ __launch_bounds__(256, 2) void kan_main(const float* __restrict__ x,
                                                   const float* __restrict__ centers,
                                                   const _Float16* __restrict__ W3,
                                                   float* __restrict__ out) {
    __shared__ _Float16 smem[2][16384];   // 2 x 32 KB (8 k-step tiles each)

    const int tid  = threadIdx.x;
    const int lane = tid & 63;
    const int w    = tid >> 6;
    const int l31  = lane & 31;
    const int sub  = lane >> 5;
    const int row0 = blockIdx.x * 128 + w * 32;

    const float* xp = x + (size_t)(row0 + l31) * NIN;   // lane's x row

    f32x16 acc[4];
#pragma unroll
    for (int nbb = 0; nbb < 4; ++nbb)
#pragma unroll
        for (int r = 0; r < 16; ++r) acc[nbb][r] = 0.f;

    const char* wbase = (const char*)W3;
#define STAGE(buf, grp)                                                         \
    do {                                                                        \
        const char* _s = wbase + (size_t)(grp) * 32768 + (size_t)tid * 16;      \
        char*       _d = (char*)&smem[(buf)][0] + (size_t)tid * 16;             \
        _Pragma("unroll")                                                       \
        for (int _i = 0; _i < 8; ++_i) gll16(_s + _i * 4096, _d + _i * 4096);   \
    } while (0)

    STAGE(0, 0);
    // prefetch x for group 0
    f32x4 xa = *(const f32x4*)(xp + sub * 8);
    f32x4 xb = *(const f32x4*)(xp + sub * 8 + 4);
    __syncthreads();

    // ---- 8 basis groups of 8 ksteps (K = 1024) ----
#pragma unroll
    for (int g = 0; g < 8; ++g) {
        const int cur = g & 1;
        STAGE(cur ^ 1, g + 1);            // g == 7 stages the silu group
        // prefetch next group's x (g=7 -> silu s=0's x)
        const int nxt = (g < 7) ? (g + 1) * 16 : 0;
        f32x4 xa2 = *(const f32x4*)(xp + nxt + sub * 8);
        f32x4 xb2 = *(const f32x4*)(xp + nxt + sub * 8 + 4);

        // pregenerate the group's 8 A-fragments (8 independent chains)
        f16x8 a[8];
#pragma unroll
        for (int t2 = 0; t2 < 4; ++t2) a[t2]     = basis8r(__builtin_fmaf(xa[t2], 3.5f, 3.5f));
#pragma unroll
        for (int t2 = 0; t2 < 4; ++t2) a[4 + t2] = basis8r(__builtin_fmaf(xb[t2], 3.5f, 3.5f));

        // MFMA cluster: 8 ksteps x 4 nbb
#pragma unroll
        for (int t2 = 0; t2 < 8; ++t2) {
            const char* bp = (const char*)&smem[cur][0] + t2 * 4096 + lane * 16;
#pragma unroll
            for (int nbb = 0; nbb < 4; ++nbb) {
                f16x8 b = *(const f16x8*)(bp + nbb * 1024);
                acc[nbb] = __builtin_amdgcn_mfma_f32_32x32x16_f16(a[t2], b, acc[nbb], 0, 0, 0);
            }
        }
        xa = xa2; xb = xb2;
        __syncthreads();
    }

    // ---- silu group: 8 ksteps (K = 128); buffer 0 holds tiles 64..71 ----
#pragma unroll
    for (int s = 0; s < 8; ++s) {
        // xa/xb hold this kstep's 8 x values; prefetch next kstep's
        f32x4 xa2, xb2;
        if (s < 7) {
            xa2 = *(const f32x4*)(xp + (s + 1) * 16 + sub * 8);
            xb2 = *(const f32x4*)(xp + (s + 1) * 16 + sub * 8 + 4);
        }
        float s0 = silu1(xa[0]), s1 = silu1(xa[1]), s2 = silu1(xa[2]), s3 = silu1(xa[3]);
        float s4 = silu1(xb[0]), s5 = silu1(xb[1]), s6 = silu1(xb[2]), s7 = silu1(xb[3]);
        pk16x2 p0 = __builtin_amdgcn_cvt_pkrtz(s0, s1);
        pk16x2 p1 = __builtin_amdgcn_cvt_pkrtz(s2, s3);
        pk16x2 p2 = __builtin_amdgcn_cvt_pkrtz(s4, s5);
        pk16x2 p3 = __builtin_amdgcn_cvt_pkrtz(s6, s7);
        f16x8 a;
        a[0] = p0[0]; a[1] = p0[1]; a[2] = p1[0]; a[3] = p1[1];
        a[4] = p2[0]; a[5] = p2[1]; a[6] = p3[0]; a[7] = p3[1];
        const char* bp = (const char*)&smem[0][0] + s * 4096 + lane * 16;
#pragma unroll
        for (int nbb = 0; nbb < 4; ++nbb) {
            f16x8 b = *(const f16x8*)(bp + nbb * 1024);
            acc[nbb] = __builtin_amdgcn_mfma_f32_32x32x16_f16(a, b, acc[nbb], 0, 0, 0);
        }
        if (s < 7) { xa = xa2; xb = xb2; }
    }

    // ---- Epilogue: row = (r&3) + 8*(r>>2) + 4*sub, col = nbb*32 + l31 ----
#pragma unroll
    for (int nbb = 0; nbb < 4; ++nbb)
#pragma unroll
        for (int r = 0; r < 16; ++r) {
            int crow = (r & 3) + 8 * (r >> 2) + 4 * sub;
            out[(size_t)(row0 + crow) * NOUT + nbb * 32 + l31] = acc[nbb][r];
        }
}

extern "C" void kernel_launch(void* const* d_in, const int* in_sizes, int n_in,
                              void* d_out, int out_size, void* d_ws, size_t ws_size,
                              hipStream_t stream) {
    const float* x       = (const float*)d_in[0];
    const float* coeffs  = (const float*)d_in[1];
    const float* base_w  = (const float*)d_in[2];
    const float* centers = (const float*)d_in[3];
    _Float16* W3 = (_Float16*)d_ws;   // 72 * 4096 = 294912 bytes

    kan_prep<<<dim3(72), dim3(256), 0, stream>>>(coeffs, base_w, W3);
    kan_main<<<dim3(BATCH / 128), dim3(256), 0, stream>>>(x, centers, W3, (float*)d_out);
}